// Round 12
// baseline (298.078 us; speedup 1.0000x reference)
//
#include <hip/hip_runtime.h>
#include <math.h>

// LocalAttention: B=2, T=2048, C=512, WINDOW=32
#define BB 2
#define TT 2048
#define CC 512
#define WIN 32
#define WSZ 63            // 2*WIN-1
#define MM (BB * TT)      // 4096
#define NWQ (3 * CC * CC) // 786432
#define NWP (CC * CC)     // 262144
#define MAGIC 0x13572468

typedef __attribute__((ext_vector_type(8))) short short8;
typedef __attribute__((ext_vector_type(4))) float floatx4;

__device__ inline unsigned short bf16_rn(float f) {
  unsigned u = __builtin_bit_cast(unsigned, f);
  u += 0x7fff + ((u >> 16) & 1);
  return (unsigned short)(u >> 16);
}
__device__ inline unsigned pack_bf16x2(float lo, float hi) {
  return (unsigned)bf16_rn(lo) | ((unsigned)bf16_rn(hi) << 16);
}

// ---------------------------------------------------------------------------
// Pre-convert weights fp32 -> bf16 (w_qkv, w_proj). 8 elems/thread, 512 blocks.
// ---------------------------------------------------------------------------
__global__ __launch_bounds__(256) void convert_w(
    const float* __restrict__ wq, const float* __restrict__ wp,
    ushort* __restrict__ wqb, ushort* __restrict__ wpb) {
  const size_t e = ((size_t)blockIdx.x * 256 + threadIdx.x) * 8;
  const float* src;
  ushort* dst;
  size_t off;
  if (e < NWQ) { src = wq; dst = wqb; off = e; }
  else { src = wp; dst = wpb; off = e - NWQ; }
  float4 v0 = ((const float4*)(src + off))[0];
  float4 v1 = ((const float4*)(src + off))[1];
  uint4 o;
  o.x = pack_bf16x2(v0.x, v0.y);
  o.y = pack_bf16x2(v0.z, v0.w);
  o.z = pack_bf16x2(v1.x, v1.y);
  o.w = pack_bf16x2(v1.z, v1.w);
  *(uint4*)(dst + off) = o;
}

// ---------------------------------------------------------------------------
// Fully fused LocalAttention. Block = 16 tokens, 512 threads (8 waves),
// grid 256 (1 block/CU, all co-resident -> flag spin is safe).
// Phase 1: QKV GEMM (m=16, n=1536, k=512). A-frags from x fp32 (inline
//   bf16 convert), B-frags from L2-resident bf16 weights. Q -> LDS;
//   K rows + transposed vT -> workspace; device-scope release flag.
// Phase 2: spin on neighbor flags (groups +-2 within batch), then r10's
//   proven QK -> softmax -> PV -> proj pipeline (K/vT from global,
//   Q/at from LDS, w_proj direct from L2).
// OOB reads: front guard + adjacent buffers, poison 0xAAAA = finite bf16;
// all garbage lands in masked S entries or P=0 columns.
// LDS 37 KB: QS (Q then at-tile, 16x520) + TB union (kbuf 16x520 /
// vbuf 512x20 / s_s 16x100 f32 + p_s 16x104).
// ---------------------------------------------------------------------------
#define SLD 100
#define PLD 104

__global__ __launch_bounds__(512) void fused_attn(
    const float* __restrict__ x, const ushort* __restrict__ wqb,
    const float* __restrict__ bqkv, const ushort* __restrict__ wpb,
    const float* __restrict__ bproj, ushort* __restrict__ kglob,
    ushort* __restrict__ vT, int* __restrict__ flags,
    float* __restrict__ out) {
  __shared__ __align__(16) ushort QS[16 * 520];   // 16640 B: Q, later at-tile
  __shared__ __align__(16) char tbraw[20480];     // kbuf | vbuf | s_s+p_s
  ushort* kbuf = (ushort*)tbraw;                  // 16 x 520
  ushort* vbuf = (ushort*)tbraw;                  // 512 x 20
  float*  s_s  = (float*)tbraw;                   // 16 x SLD
  ushort* p_s  = (ushort*)(tbraw + 16 * SLD * 4); // 16 x PLD

  const int tid = threadIdx.x;
  const int wave = tid >> 6, lane = tid & 63;
  const int mlane = lane & 15, quad = lane >> 4;
  const int blk = blockIdx.x;                     // 0..255
  const int grp = ((blk & 7) << 5) | (blk >> 3);  // XCD-contiguous groups
  const int bt0 = grp * 16;                       // 16 | 2048: no straddle
  const int b = bt0 / TT, t0 = bt0 % TT;

  // ==== Phase 1: QKV GEMM for own 16 tokens ====
  short8 af[16];
  const float* xrow = x + (size_t)(bt0 + mlane) * CC;
#pragma unroll
  for (int ks = 0; ks < 16; ++ks) {
    float4 u0 = *(const float4*)(xrow + ks * 32 + quad * 8);
    float4 u1 = *(const float4*)(xrow + ks * 32 + quad * 8 + 4);
    uint4 pk = make_uint4(pack_bf16x2(u0.x, u0.y), pack_bf16x2(u0.z, u0.w),
                          pack_bf16x2(u1.x, u1.y), pack_bf16x2(u1.z, u1.w));
    af[ks] = __builtin_bit_cast(short8, pk);
  }
  floatx4 acc[12];
#pragma unroll
  for (int j = 0; j < 12; ++j) acc[j] = (floatx4){0.f, 0.f, 0.f, 0.f};
#pragma unroll
  for (int j = 0; j < 12; ++j) {
    const int nt = wave + 8 * j;  // n-tile 0..95 (Q:0-31, K:32-63, V:64-95)
    const ushort* wrow = wqb + (size_t)(nt * 16 + mlane) * CC;
#pragma unroll
    for (int ks = 0; ks < 16; ++ks) {
      short8 bfr = *(const short8*)(wrow + ks * 32 + quad * 8);
      acc[j] = __builtin_amdgcn_mfma_f32_16x16x32_bf16(af[ks], bfr, acc[j], 0, 0, 0);
    }
  }

  // Q tiles -> QS[token][n]  (D: row=quad*4+r token, col=mlane)
#pragma unroll
  for (int j = 0; j < 4; ++j) {
    const int nt = wave + 8 * j;
    const float bn = bqkv[nt * 16 + mlane];
#pragma unroll
    for (int r = 0; r < 4; ++r)
      QS[(quad * 4 + r) * 520 + nt * 16 + mlane] = bf16_rn(acc[j][r] + bn);
  }
  // K tiles -> kbuf[token][c]
#pragma unroll
  for (int j = 4; j < 8; ++j) {
    const int nt = wave + 8 * j;
    const float bn = bqkv[nt * 16 + mlane];
#pragma unroll
    for (int r = 0; r < 4; ++r)
      kbuf[(quad * 4 + r) * 520 + (nt - 32) * 16 + mlane] = bf16_rn(acc[j][r] + bn);
  }
  __syncthreads();
  // coalesced global K rows: 16 x 64 uint4
#pragma unroll
  for (int i = 0; i < 2; ++i) {
    const int idx = tid + 512 * i;
    const int row = idx >> 6, c8 = (idx & 63) * 8;
    *(uint4*)(kglob + (size_t)(bt0 + row) * CC + c8) = *(const uint4*)(&kbuf[row * 520 + c8]);
  }
  __syncthreads();  // kbuf reads done; vbuf may overwrite
  // V tiles -> vbuf[c][token] (transpose; 4 consecutive tokens = ushort4)
#pragma unroll
  for (int j = 8; j < 12; ++j) {
    const int nt = wave + 8 * j;
    const int c = (nt - 64) * 16 + mlane;
    const float bn = bqkv[1024 + c];
    ushort4 pk4;
    pk4.x = bf16_rn(acc[j][0] + bn);
    pk4.y = bf16_rn(acc[j][1] + bn);
    pk4.z = bf16_rn(acc[j][2] + bn);
    pk4.w = bf16_rn(acc[j][3] + bn);
    *(ushort4*)(&vbuf[c * 20 + quad * 4]) = pk4;
  }
  __syncthreads();
  // coalesced vT rows: 512 c-rows x 32 B
  {
    const int c = tid;
    uint4 a0 = *(const uint4*)(&vbuf[c * 20]);
    uint4 a1 = *(const uint4*)(&vbuf[c * 20 + 8]);
    *(uint4*)(vT + (size_t)c * MM + bt0) = a0;
    *(uint4*)(vT + (size_t)c * MM + bt0 + 8) = a1;
  }
  __threadfence();
  __syncthreads();
  if (tid == 0)
    __hip_atomic_store(&flags[grp], MAGIC, __ATOMIC_RELEASE, __HIP_MEMORY_SCOPE_AGENT);
  // spin on neighbors (+-2 groups, clamped to this batch; all blocks resident)
  if (lane == 0) {
    const int gb = b * (TT / 16);
#pragma unroll
    for (int d = -2; d <= 2; ++d) {
      int gn = grp + d;
      gn = (gn < gb) ? gb : ((gn > gb + 127) ? gb + 127 : gn);
      while (__hip_atomic_load(&flags[gn], __ATOMIC_ACQUIRE, __HIP_MEMORY_SCOPE_AGENT) != MAGIC) {}
    }
  }
  __syncthreads();

  // ==== Phase 2: QK^T (rows r=0..95, src=t0-32+r, tap j=r-1-row) ====
  if (wave < 6) {
    short8 qa[16], ka[16];
#pragma unroll
    for (int ks = 0; ks < 16; ++ks)
      qa[ks] = *(const short8*)(&QS[mlane * 520 + ks * 32 + quad * 8]);
    const ushort* krow = kglob + (ptrdiff_t)(b * TT + t0 - 32 + wave * 16 + mlane) * CC;
#pragma unroll
    for (int ks = 0; ks < 16; ++ks)
      ka[ks] = *(const short8*)(krow + ks * 32 + quad * 8);
    floatx4 sa = (floatx4){0.f, 0.f, 0.f, 0.f}, sb = sa;
#pragma unroll
    for (int ks = 0; ks < 16; ks += 2) {
      sa = __builtin_amdgcn_mfma_f32_16x16x32_bf16(qa[ks], ka[ks], sa, 0, 0, 0);
      sb = __builtin_amdgcn_mfma_f32_16x16x32_bf16(qa[ks + 1], ka[ks + 1], sb, 0, 0, 0);
    }
#pragma unroll
    for (int r = 0; r < 4; ++r)
      s_s[(quad * 4 + r) * SLD + wave * 16 + mlane] = sa[r] + sb[r];
  }
  __syncthreads();

  // ---- softmax: 16 rows x 32 lanes, 3 cols each; mask j = r-1-row ----
  {
    const int row = tid >> 5, l5 = tid & 31;
    const float inv_scale = 0.044194173824159216f;  // 512^-0.5
    float e[3];
    float mx = -INFINITY;
#pragma unroll
    for (int i = 0; i < 3; ++i) {
      const int r = l5 + 32 * i;
      const int j = r - 1 - row;
      const int src = t0 - 32 + r;
      const bool valid = (j >= 0) && (j < WSZ) && (src >= 0) && (src < TT);
      e[i] = valid ? s_s[row * SLD + r] * inv_scale : -INFINITY;
      mx = fmaxf(mx, e[i]);
    }
    mx = fmaxf(mx, __shfl_xor(mx, 1));  mx = fmaxf(mx, __shfl_xor(mx, 2));
    mx = fmaxf(mx, __shfl_xor(mx, 4));  mx = fmaxf(mx, __shfl_xor(mx, 8));
    mx = fmaxf(mx, __shfl_xor(mx, 16));
    float sum = 0.f;
#pragma unroll
    for (int i = 0; i < 3; ++i) {
      e[i] = (e[i] == -INFINITY) ? 0.f : __expf(e[i] - mx);
      sum += e[i];
    }
    sum += __shfl_xor(sum, 1); sum += __shfl_xor(sum, 2);
    sum += __shfl_xor(sum, 4); sum += __shfl_xor(sum, 8);
    sum += __shfl_xor(sum, 16);
    const float rs = 1.f / sum;
#pragma unroll
    for (int i = 0; i < 3; ++i)
      p_s[row * PLD + l5 + 32 * i] = bf16_rn(e[i] * rs);
    if (l5 < 8) p_s[row * PLD + 96 + l5] = 0;  // zero k-pad cols 96..103
  }
  __syncthreads();

  // ---- PV: at[16][512] = P.V (k=96), V direct from vT[c][m]; at -> QS ----
  const ptrdiff_t mcol0 = (ptrdiff_t)b * TT + t0 - 32;
  {
    short8 pa[3];
#pragma unroll
    for (int ks = 0; ks < 3; ++ks)
      pa[ks] = *(const short8*)(&p_s[mlane * PLD + ks * 32 + quad * 8]);
    short8 vv[4][3];
#pragma unroll
    for (int i = 0; i < 4; ++i) {
      const ushort* vrow = vT + (ptrdiff_t)((wave * 4 + i) * 16 + mlane) * MM + mcol0;
#pragma unroll
      for (int ks = 0; ks < 3; ++ks)
        vv[i][ks] = *(const short8*)(vrow + ks * 32 + quad * 8);
    }
#pragma unroll
    for (int i = 0; i < 4; ++i) {
      const int nt = wave * 4 + i;  // c-tile 0..31
      floatx4 o = (floatx4){0.f, 0.f, 0.f, 0.f};
#pragma unroll
      for (int ks = 0; ks < 3; ++ks)
        o = __builtin_amdgcn_mfma_f32_16x16x32_bf16(pa[ks], vv[i][ks], o, 0, 0, 0);
#pragma unroll
      for (int r = 0; r < 4; ++r)
        QS[(quad * 4 + r) * 520 + nt * 16 + mlane] = bf16_rn(o[r]);
    }
  }
  __syncthreads();

  // ---- proj: out[16][512] = at @ w_proj^T + b_proj ----
  {
    short8 pf[16];
#pragma unroll
    for (int ks = 0; ks < 16; ++ks)
      pf[ks] = *(const short8*)(&QS[mlane * 520 + ks * 32 + quad * 8]);
#pragma unroll
    for (int i = 0; i < 4; ++i) {
      const int n = (wave * 4 + i) * 16 + mlane;
      const ushort* wrow = wpb + (size_t)n * CC;
      floatx4 oa = (floatx4){0.f, 0.f, 0.f, 0.f}, ob = oa;
#pragma unroll
      for (int ks = 0; ks < 16; ks += 2) {
        short8 b0 = *(const short8*)(wrow + ks * 32 + quad * 8);
        short8 b1 = *(const short8*)(wrow + (ks + 1) * 32 + quad * 8);
        oa = __builtin_amdgcn_mfma_f32_16x16x32_bf16(pf[ks], b0, oa, 0, 0, 0);
        ob = __builtin_amdgcn_mfma_f32_16x16x32_bf16(pf[ks + 1], b1, ob, 0, 0, 0);
      }
      const float bn = bproj[n];
#pragma unroll
      for (int r = 0; r < 4; ++r)
        out[(size_t)(bt0 + quad * 4 + r) * CC + n] = oa[r] + ob[r] + bn;
    }
  }
}

// ---------------------------------------------------------------------------
extern "C" void kernel_launch(void* const* d_in, const int* in_sizes, int n_in,
                              void* d_out, int out_size, void* d_ws, size_t ws_size,
                              hipStream_t stream) {
  const float* x      = (const float*)d_in[0];
  const float* w_qkv  = (const float*)d_in[1];
  const float* b_qkv  = (const float*)d_in[2];
  const float* w_proj = (const float*)d_in[3];
  const float* b_proj = (const float*)d_in[4];
  float* outp = (float*)d_out;

  // ws layout (ushorts). flags live in the 256KB front guard (finite bf16
  // when read as guard data). kglob's tail overruns land in wqb (finite).
  ushort* base  = (ushort*)d_ws;
  int*    flags = (int*)d_ws;                      // [0, 1KB)
  ushort* kglob = base + 131072;                   // MM x 512
  ushort* wqb   = kglob + (size_t)MM * CC;         // 1536 x 512
  ushort* wpb   = wqb + (size_t)NWQ;               // 512 x 512
  ushort* vTg   = wpb + (size_t)NWP;               // guard(64) + 512 x MM + guard
  ushort* vT    = vTg + 64;

  // 0) convert weights fp32 -> bf16
  convert_w<<<(NWQ + NWP) / (256 * 8), 256, 0, stream>>>(w_qkv, w_proj, wqb, wpb);
  // 1) fully fused qkv + attention + projection
  fused_attn<<<256, 512, 0, stream>>>(x, wqb, b_qkv, wpb, b_proj,
                                      kglob, vT, flags, outp);
}